// Round 5
// baseline (15.157 us; speedup 1.0000x reference)
//
#include <hip/hip_runtime.h>
#include <math.h>

// LDPC BP decode, fixed (3x7) H:
//   row0: vars {0,2,4,6}
//   row1: vars {1,2,5,6}
//   row2: vars {3,4,5,6}
// 2 elements per thread (independent chains -> 2x ILP at 2 waves/SIMD),
// iterations fully unrolled, all state in registers.
//
// Check node via signed tanh-product, log2-domain LLRs (m2 = m/ln2):
//   t   = exp2(-|m2|)
//   q   = t * rcp(1+t)         raw v_rcp_f32 (~1 ulp), no NR step:
//                              in the saturation band t < 2^-24, 1+t rounds
//                              to 1.0 and rcp(1.0)==1.0 exactly, so q==t and
//                              p lands on the same 2^-25 t-grid as numpy's
//                              correctly-rounded tanh; mid-range deviation
//                              ~1e-7 rel, far below grid-flip risk level.
//   p   = sign(m) * fma(-2, q, 1)
//   y_k = prod of other p's    (fwd/bwd partials; keeps the reference's
//                              product-grid in the tail)
//   c2  = log2(1+y) - log2(1-y)   (1-y Sterbenz-exact near saturation)
// Load: L2 = llr * log2e.  Store: out = tot2 * ln2.

#define LOG2E 1.4426950408889634f
#define LN2   0.6931471805599453f
#define EPT 2

__device__ __forceinline__ float p_of(float m2) {
    float t  = __builtin_amdgcn_exp2f(-fabsf(m2));
    float q  = t * __builtin_amdgcn_rcpf(1.0f + t);      // t/(1+t) in [0,0.5]
    float pm = __builtin_fmaf(-2.0f, q, 1.0f);           // |tanh|, ref grid
    unsigned s = __float_as_uint(m2) & 0x80000000u;
    return __uint_as_float(__float_as_uint(pm) | s);
}

// one check row: 4 v->c messages (log2 units) -> 4 extrinsic c->v (log2 units)
__device__ __forceinline__ void row_update(const float* m, float* c) {
    float p0 = p_of(m[0]);
    float p1 = p_of(m[1]);
    float p2 = p_of(m[2]);
    float p3 = p_of(m[3]);

    float f01 = p0 * p1;
    float b23 = p2 * p3;
    float y0 = p1 * b23;
    float y1 = p0 * b23;
    float y2 = f01 * p3;
    float y3 = f01 * p2;

    c[0] = __builtin_amdgcn_logf(1.0f + y0) - __builtin_amdgcn_logf(1.0f - y0);
    c[1] = __builtin_amdgcn_logf(1.0f + y1) - __builtin_amdgcn_logf(1.0f - y1);
    c[2] = __builtin_amdgcn_logf(1.0f + y2) - __builtin_amdgcn_logf(1.0f - y2);
    c[3] = __builtin_amdgcn_logf(1.0f + y3) - __builtin_amdgcn_logf(1.0f - y3);
}

// decode EPT independent elements in lockstep (interleaved for ILP);
// iters constant-folds at the iters==5 call site -> full unroll
__device__ __forceinline__ void decode(int iters,
                                       const float L[EPT][7], float tot[EPT][7]) {
    float m0[EPT][4], m1[EPT][4], m2[EPT][4];
#pragma unroll
    for (int e = 0; e < EPT; ++e) {
        m0[e][0] = L[e][0]; m0[e][1] = L[e][2]; m0[e][2] = L[e][4]; m0[e][3] = L[e][6];
        m1[e][0] = L[e][1]; m1[e][1] = L[e][2]; m1[e][2] = L[e][5]; m1[e][3] = L[e][6];
        m2[e][0] = L[e][3]; m2[e][1] = L[e][4]; m2[e][2] = L[e][5]; m2[e][3] = L[e][6];
    }

    for (int it = 0; it < iters; ++it) {
        float c0[EPT][4], c1[EPT][4], c2[EPT][4];
#pragma unroll
        for (int e = 0; e < EPT; ++e) {
            row_update(m0[e], c0[e]);
            row_update(m1[e], c1[e]);
            row_update(m2[e], c2[e]);
        }
#pragma unroll
        for (int e = 0; e < EPT; ++e) {
            tot[e][0] = L[e][0] + c0[e][0];
            tot[e][1] = L[e][1] + c1[e][0];
            tot[e][2] = (L[e][2] + c0[e][1]) + c1[e][1];
            tot[e][3] = L[e][3] + c2[e][0];
            tot[e][4] = (L[e][4] + c0[e][2]) + c2[e][1];
            tot[e][5] = (L[e][5] + c1[e][2]) + c2[e][2];
            tot[e][6] = ((L[e][6] + c0[e][3]) + c1[e][3]) + c2[e][3];

            m0[e][0] = tot[e][0] - c0[e][0];
            m0[e][1] = tot[e][2] - c0[e][1];
            m0[e][2] = tot[e][4] - c0[e][2];
            m0[e][3] = tot[e][6] - c0[e][3];
            m1[e][0] = tot[e][1] - c1[e][0];
            m1[e][1] = tot[e][2] - c1[e][1];
            m1[e][2] = tot[e][5] - c1[e][2];
            m1[e][3] = tot[e][6] - c1[e][3];
            m2[e][0] = tot[e][3] - c2[e][0];
            m2[e][1] = tot[e][4] - c2[e][1];
            m2[e][2] = tot[e][5] - c2[e][2];
            m2[e][3] = tot[e][6] - c2[e][3];
        }
    }
}

__global__ __launch_bounds__(256) void ldpc_bp_kernel(
        const float* __restrict__ llr,
        const int*   __restrict__ iters_p,
        float*       __restrict__ out,
        int B) {
    const int half = (B + EPT - 1) / EPT;
    int tid = blockIdx.x * blockDim.x + threadIdx.x;
    if (tid >= half) return;
    const int iters = iters_p[0];

    int   idx[EPT];
    bool  ok[EPT];
    float L2[EPT][7], tot2[EPT][7];
#pragma unroll
    for (int e = 0; e < EPT; ++e) {
        idx[e] = tid + e * half;
        ok[e]  = idx[e] < B;
        const float* Lp = llr + (size_t)(ok[e] ? idx[e] : 0) * 7;
#pragma unroll
        for (int j = 0; j < 7; ++j) {
            L2[e][j]  = Lp[j] * LOG2E;   // -> log2-domain LLR units
            tot2[e][j] = L2[e][j];
        }
    }

    if (iters == 5) {
        decode(5, L2, tot2);             // constant trip count -> full unroll
    } else {
        decode(iters, L2, tot2);
    }

#pragma unroll
    for (int e = 0; e < EPT; ++e) {
        if (!ok[e]) continue;
        float* Op = out + (size_t)idx[e] * 7;
#pragma unroll
        for (int j = 0; j < 7; ++j) Op[j] = tot2[e][j] * LN2;
    }
}

extern "C" void kernel_launch(void* const* d_in, const int* in_sizes, int n_in,
                              void* d_out, int out_size, void* d_ws, size_t ws_size,
                              hipStream_t stream) {
    (void)n_in; (void)d_ws; (void)ws_size;
    const float* llr  = (const float*)d_in[0];
    const int*   mi   = (const int*)d_in[1];
    float*       out  = (float*)d_out;
    const int B = in_sizes[0] / 7;
    const int half = (B + EPT - 1) / EPT;
    const int block = 256;
    const int grid = (half + block - 1) / block;
    ldpc_bp_kernel<<<grid, block, 0, stream>>>(llr, mi, out, B);
}

// Round 6
// 12.439 us; speedup vs baseline: 1.2185x; 1.2185x over previous
//
#include <hip/hip_runtime.h>
#include <math.h>

// LDPC BP decode, fixed (3x7) H:
//   row A (0): vars {0,2,4,6}     v0 deg-1
//   row B (1): vars {1,2,5,6}     v1 deg-1
//   row C (2): vars {3,4,5,6}     v3 deg-1
// One thread per element, fully unrolled, all state in registers.
//
// Signed tanh-product check node, log2-domain LLRs (m2 = m/ln2):
//   t  = exp2(-|m2|);  q = t*rcp(1+t);  p = copysign(fma(-2,q,1), m2)
//   y  = extrinsic product of p's (same mul order as the round-4 kernel
//        -> bit-identical tail grid);  c = log2(1+y) - log2(1-y)
// Structural cuts vs round 4 (all bit-safe, Dc <= ~ulp by the
// perturbed-factor bound Dc <= Dp_j/(1-p_j)):
//   - deg-1 p's (v0,v1,v3) are loop-invariant -> hoisted
//   - middle iterations: only the 9 consumed c's computed (deg-1 c's and
//     tot are dead until the final iteration)
//   - m-updates via direct extrinsic sums m = L + c_other (no tot detour)
// Load: L2 = llr*log2e.  Store: out = tot*ln2.

#define LOG2E 1.4426950408889634f
#define LN2   0.6931471805599453f

__device__ __forceinline__ float p_of(float m2) {
    float t  = __builtin_amdgcn_exp2f(-fabsf(m2));
    float q  = t * __builtin_amdgcn_rcpf(1.0f + t);   // t/(1+t) in [0,0.5]
    float pm = __builtin_fmaf(-2.0f, q, 1.0f);        // |tanh|, ref grid
    return __builtin_copysignf(pm, m2);
}

__device__ __forceinline__ float c_of(float y) {
    return __builtin_amdgcn_logf(1.0f + y) - __builtin_amdgcn_logf(1.0f - y);
}

// iters constant-folds at the iters==5 call site -> full unroll
__device__ __forceinline__ void decode(int iters, const float L[7], float tot[7]) {
    // deg-1 edge p's: loop-invariant
    const float pA0 = p_of(L[0]);
    const float pB0 = p_of(L[1]);
    const float pC0 = p_of(L[3]);

    // varying v->c messages (log2-domain LLR units)
    float mA1 = L[2], mA2 = L[4], mA3 = L[6];   // row A -> v2, v4, v6
    float mB1 = L[2], mB2 = L[5], mB3 = L[6];   // row B -> v2, v5, v6
    float mC1 = L[4], mC2 = L[5], mC3 = L[6];   // row C -> v4, v5, v6

    for (int it = 0; it < iters - 1; ++it) {
        float pA1 = p_of(mA1), pA2 = p_of(mA2), pA3 = p_of(mA3);
        float pB1 = p_of(mB1), pB2 = p_of(mB2), pB3 = p_of(mB3);
        float pC1 = p_of(mC1), pC2 = p_of(mC2), pC3 = p_of(mC3);

        float fA = pA0 * pA1, bA = pA2 * pA3;
        float fB = pB0 * pB1, bB = pB2 * pB3;
        float fC = pC0 * pC1, bC = pC2 * pC3;

        // only the 9 consumed c's (deg-1 targets skipped in middle iters)
        float cA1 = c_of(pA0 * bA);   // A -> v2
        float cA2 = c_of(fA * pA3);   // A -> v4
        float cA3 = c_of(fA * pA2);   // A -> v6
        float cB1 = c_of(pB0 * bB);   // B -> v2
        float cB2 = c_of(fB * pB3);   // B -> v5
        float cB3 = c_of(fB * pB2);   // B -> v6
        float cC1 = c_of(pC0 * bC);   // C -> v4
        float cC2 = c_of(fC * pC3);   // C -> v5
        float cC3 = c_of(fC * pC2);   // C -> v6

        // direct extrinsic sums
        mA1 = L[2] + cB1;
        mB1 = L[2] + cA1;
        mA2 = L[4] + cC1;
        mC1 = L[4] + cA2;
        mB2 = L[5] + cC2;
        mC2 = L[5] + cB2;
        float s01 = cA3 + cB3, s02 = cA3 + cC3, s12 = cB3 + cC3;
        mA3 = L[6] + s12;
        mB3 = L[6] + s02;
        mC3 = L[6] + s01;
    }

    if (iters > 0) {
        // final iteration: all 12 c's + totals (same add order as round 4)
        float pA1 = p_of(mA1), pA2 = p_of(mA2), pA3 = p_of(mA3);
        float pB1 = p_of(mB1), pB2 = p_of(mB2), pB3 = p_of(mB3);
        float pC1 = p_of(mC1), pC2 = p_of(mC2), pC3 = p_of(mC3);

        float fA = pA0 * pA1, bA = pA2 * pA3;
        float fB = pB0 * pB1, bB = pB2 * pB3;
        float fC = pC0 * pC1, bC = pC2 * pC3;

        float cA0 = c_of(pA1 * bA);
        float cA1 = c_of(pA0 * bA);
        float cA2 = c_of(fA * pA3);
        float cA3 = c_of(fA * pA2);
        float cB0 = c_of(pB1 * bB);
        float cB1 = c_of(pB0 * bB);
        float cB2 = c_of(fB * pB3);
        float cB3 = c_of(fB * pB2);
        float cC0 = c_of(pC1 * bC);
        float cC1 = c_of(pC0 * bC);
        float cC2 = c_of(fC * pC3);
        float cC3 = c_of(fC * pC2);

        tot[0] = L[0] + cA0;
        tot[1] = L[1] + cB0;
        tot[3] = L[3] + cC0;
        tot[2] = (L[2] + cA1) + cB1;
        tot[4] = (L[4] + cA2) + cC1;
        tot[5] = (L[5] + cB2) + cC2;
        tot[6] = ((L[6] + cA3) + cB3) + cC3;
    }
}

__global__ __launch_bounds__(256) void ldpc_bp_kernel(
        const float* __restrict__ llr,
        const int*   __restrict__ iters_p,
        float*       __restrict__ out,
        int B) {
    int b = blockIdx.x * blockDim.x + threadIdx.x;
    if (b >= B) return;
    const int iters = iters_p[0];

    const float* Lp = llr + (size_t)b * 7;
    float L2[7], tot[7];
#pragma unroll
    for (int j = 0; j < 7; ++j) {
        L2[j] = Lp[j] * LOG2E;   // -> log2-domain LLR units
        tot[j] = L2[j];
    }

    if (iters == 5) {
        decode(5, L2, tot);      // constant trip count -> full unroll
    } else {
        decode(iters, L2, tot);
    }

    float* Op = out + (size_t)b * 7;
#pragma unroll
    for (int j = 0; j < 7; ++j) Op[j] = tot[j] * LN2;
}

extern "C" void kernel_launch(void* const* d_in, const int* in_sizes, int n_in,
                              void* d_out, int out_size, void* d_ws, size_t ws_size,
                              hipStream_t stream) {
    (void)n_in; (void)d_ws; (void)ws_size;
    const float* llr  = (const float*)d_in[0];
    const int*   mi   = (const int*)d_in[1];
    float*       out  = (float*)d_out;
    const int B = in_sizes[0] / 7;
    const int block = 256;
    const int grid = (B + block - 1) / block;
    ldpc_bp_kernel<<<grid, block, 0, stream>>>(llr, mi, out, B);
}

// Round 7
// 12.012 us; speedup vs baseline: 1.2618x; 1.0356x over previous
//
#include <hip/hip_runtime.h>
#include <math.h>

// LDPC BP decode, fixed (3x7) H:
//   row A: vars {0,2,4,6}   v0 deg-1
//   row B: vars {1,2,5,6}   v1 deg-1
//   row C: vars {3,4,5,6}   v3 deg-1
// One thread per element, fully unrolled, all state in registers.
//
// Belief state kept MULTIPLICATIVELY: t = e^{-m} > 0 (t>1 <=> m<0).
//   p = tanh(m/2):  u = rcp(1+t); q = t*u;
//                   p = copysign(fma(-2, min(q,u), 1), u-q)
//     - t<=1 path (min=q) is bit-identical to the round-6 validated form
//     - t>1 path (min=u) keeps the fine grid and saturates |p|->1.0 at
//       |m|=18.0 exactly like numpy tanh (the ceiling c<=17.33 that sets
//       the reference's output scale survives on BOTH sign sides)
//   y_k = extrinsic product of p's (same mul trees as rounds 4-6)
//   message update: t = tL * prod tau,  tau = e^{-c} = (1-y)*rcp(1+y)
//     (replaces 2 logs + exp2 with ONE rcp; 1+y,1-y Sterbenz-exact near
//      saturation so the quantization lattice matches the reference)
//   output: tot_var = -log2(tL * prod tau_edge) * ln2   (one log per var)
// Trans-op budget (measured T~32cyc each, the bottleneck): 110 vs 192.

#define LOG2E 1.4426950408889634f
#define LN2   0.6931471805599453f

__device__ __forceinline__ float p_of(float t) {
    float u  = __builtin_amdgcn_rcpf(1.0f + t);
    float q  = t * u;
    float mn = __builtin_fminf(q, u);
    float mag = __builtin_fmaf(-2.0f, mn, 1.0f);
    return __builtin_copysignf(mag, u - q);     // sign(m) == sign(1-t)
}

__device__ __forceinline__ float tau_of(float y) {
    return (1.0f - y) * __builtin_amdgcn_rcpf(1.0f + y);   // e^{-c}
}

// tot2 pre-filled with L2 (covers iters==0); iters constant-folds at the
// iters==5 call site -> full unroll
__device__ __forceinline__ void decode(int iters, const float tL[7], float tot2[7]) {
    if (iters <= 0) return;

    // deg-1 edge p's: loop-invariant
    const float pA0 = p_of(tL[0]);
    const float pB0 = p_of(tL[1]);
    const float pC0 = p_of(tL[3]);

    // varying edge beliefs t = e^{-m}
    float tA2 = tL[2], tA4 = tL[4], tA6 = tL[6];
    float tB2 = tL[2], tB5 = tL[5], tB6 = tL[6];
    float tC4 = tL[4], tC5 = tL[5], tC6 = tL[6];

    for (int it = 0; it < iters - 1; ++it) {
        float pA2 = p_of(tA2), pA4 = p_of(tA4), pA6 = p_of(tA6);
        float pB2 = p_of(tB2), pB5 = p_of(tB5), pB6 = p_of(tB6);
        float pC4 = p_of(tC4), pC5 = p_of(tC5), pC6 = p_of(tC6);

        // extrinsic products for the 9 consumed c's
        float gA1 = pA0 * pA4, gA2 = pA0 * pA2;
        float yA2 = gA1 * pA6, yA4 = gA2 * pA6, yA6 = gA2 * pA4;
        float gB1 = pB0 * pB5, gB2 = pB0 * pB2;
        float yB2 = gB1 * pB6, yB5 = gB2 * pB6, yB6 = gB2 * pB5;
        float gC1 = pC0 * pC5, gC2 = pC0 * pC4;
        float yC4 = gC1 * pC6, yC5 = gC2 * pC6, yC6 = gC2 * pC5;

        float uA2 = tau_of(yA2), uA4 = tau_of(yA4), uA6 = tau_of(yA6);
        float uB2 = tau_of(yB2), uB5 = tau_of(yB5), uB6 = tau_of(yB6);
        float uC4 = tau_of(yC4), uC5 = tau_of(yC5), uC6 = tau_of(yC6);

        // t = tL * prod of other-rows' tau at the same var
        tA2 = tL[2] * uB2;  tB2 = tL[2] * uA2;
        tA4 = tL[4] * uC4;  tC4 = tL[4] * uA4;
        tB5 = tL[5] * uC5;  tC5 = tL[5] * uB5;
        float wBC = uB6 * uC6, wAC = uA6 * uC6, wAB = uA6 * uB6;
        tA6 = tL[6] * wBC;  tB6 = tL[6] * wAC;  tC6 = tL[6] * wAB;
    }

    // final iteration: all 12 c's folded into per-var totals
    {
        float pA2 = p_of(tA2), pA4 = p_of(tA4), pA6 = p_of(tA6);
        float pB2 = p_of(tB2), pB5 = p_of(tB5), pB6 = p_of(tB6);
        float pC4 = p_of(tC4), pC5 = p_of(tC5), pC6 = p_of(tC6);

        float fA = pA0 * pA2, bA = pA4 * pA6;
        float yA0 = pA2 * bA, yA2 = pA0 * bA, yA4 = fA * pA6, yA6 = fA * pA4;
        float fB = pB0 * pB2, bB = pB5 * pB6;
        float yB1 = pB2 * bB, yB2 = pB0 * bB, yB5 = fB * pB6, yB6 = fB * pB5;
        float fC = pC0 * pC4, bC = pC5 * pC6;
        float yC3 = pC4 * bC, yC4 = pC0 * bC, yC5 = fC * pC6, yC6 = fC * pC5;

        float uA0 = tau_of(yA0), uA2 = tau_of(yA2), uA4 = tau_of(yA4), uA6 = tau_of(yA6);
        float uB1 = tau_of(yB1), uB2 = tau_of(yB2), uB5 = tau_of(yB5), uB6 = tau_of(yB6);
        float uC3 = tau_of(yC3), uC4 = tau_of(yC4), uC5 = tau_of(yC5), uC6 = tau_of(yC6);

        float T0 = tL[0] * uA0;
        float T1 = tL[1] * uB1;
        float T3 = tL[3] * uC3;
        float T2 = tL[2] * (uA2 * uB2);
        float T4 = tL[4] * (uA4 * uC4);
        float T5 = tL[5] * (uB5 * uC5);
        float T6 = tL[6] * (uA6 * (uB6 * uC6));

        tot2[0] = -__builtin_amdgcn_logf(T0);
        tot2[1] = -__builtin_amdgcn_logf(T1);
        tot2[2] = -__builtin_amdgcn_logf(T2);
        tot2[3] = -__builtin_amdgcn_logf(T3);
        tot2[4] = -__builtin_amdgcn_logf(T4);
        tot2[5] = -__builtin_amdgcn_logf(T5);
        tot2[6] = -__builtin_amdgcn_logf(T6);
    }
}

__global__ __launch_bounds__(256) void ldpc_bp_kernel(
        const float* __restrict__ llr,
        const int*   __restrict__ iters_p,
        float*       __restrict__ out,
        int B) {
    int b = blockIdx.x * blockDim.x + threadIdx.x;
    if (b >= B) return;
    const int iters = iters_p[0];

    const float* Lp = llr + (size_t)b * 7;
    float tL[7], tot2[7];
#pragma unroll
    for (int j = 0; j < 7; ++j) {
        float L2 = Lp[j] * LOG2E;                    // log2-domain LLR
        tot2[j] = L2;                                // iters==0 fallback
        tL[j]   = __builtin_amdgcn_exp2f(-L2);       // t = e^{-L}
    }

    if (iters == 5) {
        decode(5, tL, tot2);     // constant trip count -> full unroll
    } else {
        decode(iters, tL, tot2);
    }

    float* Op = out + (size_t)b * 7;
#pragma unroll
    for (int j = 0; j < 7; ++j) Op[j] = tot2[j] * LN2;
}

extern "C" void kernel_launch(void* const* d_in, const int* in_sizes, int n_in,
                              void* d_out, int out_size, void* d_ws, size_t ws_size,
                              hipStream_t stream) {
    (void)n_in; (void)d_ws; (void)ws_size;
    const float* llr  = (const float*)d_in[0];
    const int*   mi   = (const int*)d_in[1];
    float*       out  = (float*)d_out;
    const int B = in_sizes[0] / 7;
    const int block = 256;
    const int grid = (B + block - 1) / block;
    ldpc_bp_kernel<<<grid, block, 0, stream>>>(llr, mi, out, B);
}